// Round 8
// baseline (1537.367 us; speedup 1.0000x reference)
//
#include <hip/hip_runtime.h>

#define IN_F 128
#define HID  128
#define NB_SHIFT 7        // 128 nodes per bucket
#define NBKT 1024         // padded bucket count (real NB = ceil(N/128) = 782)
#define NCHUNK 256        // edge chunks for count/scatter passes

typedef __bf16 bf16x8 __attribute__((ext_vector_type(8)));
typedef float f32x4 __attribute__((ext_vector_type(4)));
union U8 { uint4 u; bf16x8 v; };

// ---- bf16 helpers (RNE pack, shift-unpack) --------------------------------
__device__ __forceinline__ unsigned int bfround(float x) {
    unsigned int u = __float_as_uint(x);
    return (u + 0x7fffu + ((u >> 16) & 1u)) >> 16;
}
__device__ __forceinline__ unsigned int pack2(float a, float b) {
    return bfround(a) | (bfround(b) << 16);
}
__device__ __forceinline__ float lo_f(unsigned int u) { return __uint_as_float(u << 16); }
__device__ __forceinline__ float hi_f(unsigned int u) { return __uint_as_float(u & 0xffff0000u); }

// ---------------------------------------------------------------------------
// Pass A: per-chunk histograms of BOTH src and dst buckets (LDS atomics)
// ---------------------------------------------------------------------------
__global__ __launch_bounds__(256)
void countAB_kernel(const int* __restrict__ src, const int* __restrict__ dst,
                    int* __restrict__ cd, int* __restrict__ cs, int E, int epc) {
    __shared__ int hd[NBKT], hs[NBKT];
    int tid = threadIdx.x, c = blockIdx.x;
    for (int i = tid; i < NBKT; i += 256) { hd[i] = 0; hs[i] = 0; }
    __syncthreads();
    int lo = c * epc, hi = min(lo + epc, E);
    for (int i = lo + tid; i < hi; i += 256) {
        atomicAdd(&hd[dst[i] >> NB_SHIFT], 1);
        atomicAdd(&hs[src[i] >> NB_SHIFT], 1);
    }
    __syncthreads();
    for (int i = tid; i < NBKT; i += 256) {
        cd[c * NBKT + i] = hd[i];
        cs[c * NBKT + i] = hs[i];
    }
}

// ---------------------------------------------------------------------------
// Pass B1: per-bucket exclusive scan over chunks (in place), bucket totals out
// grid = 2*NBKT: first half dst, second half src
// ---------------------------------------------------------------------------
__global__ __launch_bounds__(256)
void scanB1_kernel(int* __restrict__ cd, int* __restrict__ cs,
                   int* __restrict__ btd, int* __restrict__ bts) {
    __shared__ int sd[256];
    int b = blockIdx.x, tid = threadIdx.x;
    int* arr = (b < NBKT) ? cd : cs;
    int* bt  = (b < NBKT) ? btd : bts;
    int col = b & (NBKT - 1);
    int v = arr[tid * NBKT + col];
    sd[tid] = v; __syncthreads();
    for (int off = 1; off < 256; off <<= 1) {
        int t = (tid >= off) ? sd[tid - off] : 0;
        __syncthreads();
        sd[tid] += t;
        __syncthreads();
    }
    arr[tid * NBKT + col] = sd[tid] - v;
    if (tid == 255) bt[col] = sd[255];
}

// ---------------------------------------------------------------------------
// Pass B2: blocks 0,1 = exclusive scans of 1024 bucket totals (dst, src);
// blocks 2..17 = pack W1 -> bf16-transposed w1tb [c][k2]
// ---------------------------------------------------------------------------
__global__ __launch_bounds__(512)
void scanB2_kernel(const int* __restrict__ btd, const int* __restrict__ bts,
                   int* __restrict__ bbd, int* __restrict__ bbs,
                   const float* __restrict__ W1, unsigned int* __restrict__ w1tb,
                   int N, int E) {
    int tid = threadIdx.x;
    if (blockIdx.x >= 2) {
        int idx = (blockIdx.x - 2) * 512 + tid;
        int c = idx & 127, k2 = idx >> 7;
        float a = W1[(2 * k2)     * HID + c];
        float b = W1[(2 * k2 + 1) * HID + c];
        w1tb[c * 64 + k2] = pack2(a, b);
        return;
    }
    __shared__ int sd[512];
    const int* bt = blockIdx.x ? bts : btd;
    int* bb = blockIdx.x ? bbs : bbd;
    // 1024 elements, 2 per thread
    int v0 = bt[2 * tid], v1 = bt[2 * tid + 1];
    int sum = v0 + v1;
    sd[tid] = sum; __syncthreads();
    for (int off = 1; off < 512; off <<= 1) {
        int t = (tid >= off) ? sd[tid - off] : 0;
        __syncthreads();
        sd[tid] += t;
        __syncthreads();
    }
    int excl = sd[tid] - sum;
    bb[2 * tid]     = excl;
    bb[2 * tid + 1] = excl + v0;
    if (tid == 511) bb[NBKT] = sd[511];  // == E
}

// ---------------------------------------------------------------------------
// Pass C: scatter packed dst-pairs (src | dlow<<17) + src low-7-bits bytes
// into bucket regions (LDS cursors, no global atomics)
// ---------------------------------------------------------------------------
__global__ __launch_bounds__(256)
void scatterAB_kernel(const int* __restrict__ src, const int* __restrict__ dst,
                      const int* __restrict__ cd, const int* __restrict__ cs,
                      const int* __restrict__ bbd, const int* __restrict__ bbs,
                      int* __restrict__ pairs, unsigned char* __restrict__ sbytes,
                      int E, int epc) {
    __shared__ int curd[NBKT], curs[NBKT];
    int tid = threadIdx.x, c = blockIdx.x;
    for (int i = tid; i < NBKT; i += 256) {
        curd[i] = cd[c * NBKT + i] + bbd[i];
        curs[i] = cs[c * NBKT + i] + bbs[i];
    }
    __syncthreads();
    int lo = c * epc, hi = min(lo + epc, E);
    for (int i = lo + tid; i < hi; i += 256) {
        int s = src[i], d = dst[i];
        int pd = atomicAdd(&curd[d >> NB_SHIFT], 1);
        pairs[pd] = s | ((d & 127) << 17);          // src < 2^17, dlow 7 bits
        int ps = atomicAdd(&curs[s >> NB_SHIFT], 1);
        sbytes[ps] = (unsigned char)(s & 127);
    }
}

// ---------------------------------------------------------------------------
// Pass D (src): per-bucket byte histogram -> ninv_out
// ---------------------------------------------------------------------------
__global__ __launch_bounds__(256)
void buildDsrc_kernel(const unsigned char* __restrict__ sbytes, const int* __restrict__ bbs,
                      float* __restrict__ ninv_out, int N) {
    __shared__ int cnt[128];
    int b = blockIdx.x, tid = threadIdx.x;
    if (tid < 128) cnt[tid] = 0;
    __syncthreads();
    int beg = bbs[b], end = bbs[b + 1];
    for (int i = beg + tid; i < end; i += 256)
        atomicAdd(&cnt[sbytes[i]], 1);
    __syncthreads();
    int node = (b << NB_SHIFT) + tid;
    if (tid < 128 && node < N) {
        int v = cnt[tid];
        ninv_out[node] = (v > 0) ? rsqrtf((float)v) : 0.0f;
    }
}

// ---------------------------------------------------------------------------
// conv: xb = bf16(in_feat * ninv_out)
// ---------------------------------------------------------------------------
__global__ __launch_bounds__(256)
void conv_kernel(const float* __restrict__ in_feat, const float* __restrict__ ninv_out,
                 unsigned int* __restrict__ xb, int N) {
    int gid = blockIdx.x * 256 + threadIdx.x;   // [0, N*32)
    if (gid >= N * 32) return;
    int r = gid >> 5, q = gid & 31;
    float no = ninv_out[r];
    float4 v = ((const float4*)in_feat)[(long)r * 32 + q];
    uint2 o;
    o.x = pack2(v.x * no, v.y * no);
    o.y = pack2(v.z * no, v.w * no);
    ((uint2*)xb)[(long)r * 32 + q] = o;
}

// ---------------------------------------------------------------------------
// Layer-1 aggregation, bucket-level LDS f32 accumulate (no CSR, no eidx):
// one block per 128-node bucket; streams the bucket's pairs; lanes 0-31 cover
// even edge of each pair slot, 32-63 odd; 4x ds_add_f32 per edge-half.
// LDS slot = n*132 + (f&3)*32 + (f>>2)  -> bank (4n+hl)%32, conflict-free.
// Also produces ninv_in from an LDS edge-count histogram.
// ---------------------------------------------------------------------------
__global__ __launch_bounds__(512, 2)
void agg1_kernel(const unsigned int* __restrict__ xb, const int* __restrict__ pairs,
                 const int* __restrict__ bbd, unsigned int* __restrict__ Bb,
                 float* __restrict__ ninv_in, int N) {
    __shared__ float acc[128 * 132];   // 67.6 KB
    __shared__ int cnt[128];
    int tid = threadIdx.x;
    int b = blockIdx.x;
    int node0 = b << NB_SHIFT;
    for (int i = tid; i < 128 * 132; i += 512) acc[i] = 0.f;
    if (tid < 128) cnt[tid] = 0;
    __syncthreads();

    int beg = bbd[b], end = bbd[b + 1];
    int wave = tid >> 6, lane = tid & 63, half = lane >> 5, hl = lane & 31;
    const uint2* x2 = (const uint2*)xb;

    // 8 edges per wave-iteration (4 uint2 gathers in flight), waves strided
    for (int j0 = beg + wave * 8; j0 < end; j0 += 64) {
        bool vs[4]; int ns[4]; uint2 us[4];
#pragma unroll
        for (int t = 0; t < 4; ++t) {
            int j2 = j0 + 2 * t + half;
            vs[t] = j2 < end;
            int p = vs[t] ? pairs[j2] : 0;
            ns[t] = (p >> 17) & 127;
            int s = p & 0x1FFFF;
            us[t] = vs[t] ? x2[(long)s * 32 + hl] : make_uint2(0u, 0u);
        }
#pragma unroll
        for (int t = 0; t < 4; ++t) {
            if (vs[t]) {
                float* base = &acc[ns[t] * 132];
                atomicAdd(base +       hl, lo_f(us[t].x));
                atomicAdd(base +  32 + hl, hi_f(us[t].x));
                atomicAdd(base +  64 + hl, lo_f(us[t].y));
                atomicAdd(base +  96 + hl, hi_f(us[t].y));
                if (hl == 0) atomicAdd(&cnt[ns[t]], 1);
            }
        }
    }
    __syncthreads();

    // ninv_in
    if (tid < 128) {
        int node = node0 + tid;
        if (node < N) {
            int v = cnt[tid];
            ninv_in[node] = (v > 0) ? rsqrtf((float)v) : 0.0f;
        }
    }
    // convert acc -> packed bf16 rows of Bb (feat f at slot (f&3)*32 + (f>>2))
    for (int i = tid; i < 128 * 64; i += 512) {
        int n = i >> 6, q = i & 63;
        int node = node0 + n;
        if (node >= N) continue;
        int f0 = 2 * q, f1 = 2 * q + 1;
        float a = acc[n * 132 + (f0 & 3) * 32 + (f0 >> 2)];
        float c = acc[n * 132 + (f1 & 3) * 32 + (f1 >> 2)];
        Bb[(long)node * 64 + q] = pack2(a, c);
    }
}

// ---------------------------------------------------------------------------
// Fused mm1+mm2 via MFMA (bf16 in, f32 accum):
//   t[row] = ninv_out[row] * (relu(B[row]@W1 * ninv_in + b1) @ W2)
// ---------------------------------------------------------------------------
#define MM_ROWS 64
__global__ __launch_bounds__(256)
void mm1_kernel(const unsigned int* __restrict__ Bb, const unsigned int* __restrict__ w1tb,
                const float* __restrict__ b1, const float* __restrict__ ninv_in,
                const float* __restrict__ ninv_out, const float* __restrict__ W2,
                float* __restrict__ t, int N) {
    __shared__ unsigned int w1t[128 * 68];    // [c][k2], padded stride 68
    int tid = threadIdx.x;
    int wave = tid >> 6, lane = tid & 63;
    int row0 = blockIdx.x * MM_ROWS;

    {
        const uint4* g = (const uint4*)w1tb;
#pragma unroll
        for (int pass = 0; pass < 8; ++pass) {
            int idx = pass * 256 + tid;       // uint4 index
            int c = idx >> 4, q = idx & 15;
            *(uint4*)&w1t[c * 68 + q * 4] = g[idx];
        }
    }

    int m = lane & 15;
    int kg = lane >> 4;                        // 0..3
    float  b1r[8];
    float2 w2r[8];
    const float2* W2v = (const float2*)W2;
#pragma unroll
    for (int ct = 0; ct < 8; ++ct) {
        int n = m + 16 * ct;
        b1r[ct] = b1[n];
        w2r[ct] = W2v[n];
    }

    int r = row0 + wave * 16 + m;
    U8 afrag[4];
    if (r < N) {
#pragma unroll
        for (int ks = 0; ks < 4; ++ks)
            afrag[ks].u = *(const uint4*)&Bb[(long)r * 64 + ks * 16 + kg * 4];
    } else {
#pragma unroll
        for (int ks = 0; ks < 4; ++ks)
            afrag[ks].u = make_uint4(0u, 0u, 0u, 0u);
    }
    __syncthreads();

    f32x4 acc[8];
#pragma unroll
    for (int ct = 0; ct < 8; ++ct) acc[ct] = (f32x4){0.f, 0.f, 0.f, 0.f};

#pragma unroll
    for (int ks = 0; ks < 4; ++ks) {
#pragma unroll
        for (int ct = 0; ct < 8; ++ct) {
            U8 bf;
            bf.u = *(const uint4*)&w1t[(m + 16 * ct) * 68 + ks * 16 + kg * 4];
            acc[ct] = __builtin_amdgcn_mfma_f32_16x16x32_bf16(afrag[ks].v, bf.v, acc[ct], 0, 0, 0);
        }
    }

#pragma unroll
    for (int reg = 0; reg < 4; ++reg) {
        int grow = row0 + wave * 16 + kg * 4 + reg;
        int cg = min(grow, N - 1);
        float ni = ninv_in[cg];
        float p0 = 0.f, p1 = 0.f;
#pragma unroll
        for (int ct = 0; ct < 8; ++ct) {
            float h = fmaxf(acc[ct][reg] * ni + b1r[ct], 0.f);
            p0 += h * w2r[ct].x;
            p1 += h * w2r[ct].y;
        }
#pragma unroll
        for (int off = 8; off >= 1; off >>= 1) {
            p0 += __shfl_xor(p0, off, 16);
            p1 += __shfl_xor(p1, off, 16);
        }
        if (m == 0 && grow < N) {
            float no = ninv_out[grow];
            ((float2*)t)[grow] = make_float2(p0 * no, p1 * no);
        }
    }
}

// ---------------------------------------------------------------------------
// Layer-2: bucket-level LDS accumulate of t[src] over dst, fused epilogue
// ---------------------------------------------------------------------------
__global__ __launch_bounds__(256)
void final2_kernel(const float* __restrict__ t, const int* __restrict__ pairs,
                   const int* __restrict__ bbd, const float* __restrict__ ninv_in,
                   const float* __restrict__ b2, float* __restrict__ out, int N) {
    __shared__ float acc2[256];    // 128 nodes x 2
    int tid = threadIdx.x, b = blockIdx.x;
    int node0 = b << NB_SHIFT;
    acc2[tid] = 0.f;
    __syncthreads();
    int beg = bbd[b], end = bbd[b + 1];
    const float2* t2 = (const float2*)t;
    for (int i = beg + tid; i < end; i += 256) {
        int p = pairs[i];
        int n = (p >> 17) & 127;
        float2 v = t2[p & 0x1FFFF];
        atomicAdd(&acc2[n * 2 + 0], v.x);
        atomicAdd(&acc2[n * 2 + 1], v.y);
    }
    __syncthreads();
    if (tid < 128) {
        int node = node0 + tid;
        if (node < N) {
            float ni = ninv_in[node];
            ((float2*)out)[node] = make_float2(acc2[tid * 2] * ni + b2[0],
                                               acc2[tid * 2 + 1] * ni + b2[1]);
        }
    }
}

// ---------------------------------------------------------------------------
extern "C" void kernel_launch(void* const* d_in, const int* in_sizes, int n_in,
                              void* d_out, int out_size, void* d_ws, size_t ws_size,
                              hipStream_t stream) {
    const float* in_feat = (const float*)d_in[0];
    const float* W1      = (const float*)d_in[1];
    const float* b1      = (const float*)d_in[2];
    const float* W2      = (const float*)d_in[3];
    const float* b2      = (const float*)d_in[4];
    const int*   src     = (const int*)d_in[5];
    const int*   dst     = (const int*)d_in[6];
    int N = in_sizes[0] / IN_F;
    int E = in_sizes[5];
    int NB = (N + 127) >> NB_SHIFT;      // 128-node buckets

    // workspace layout
    unsigned int* Bb   = (unsigned int*)d_ws;                 // 64N uints
    unsigned int* xb   = Bb + (size_t)64 * N;                 // 64N uints
    int*   pairs       = (int*)(xb + (size_t)64 * N);         // E ints (own region!)
    unsigned char* sbytes = (unsigned char*)(pairs + E);      // E bytes
    float* ninv_out    = (float*)(sbytes + ((E + 3) & ~3));   // N
    float* ninv_in     = ninv_out + N;                        // N
    float* t           = ninv_in + N;                         // 2N
    int*   cd          = (int*)(t + (size_t)2 * N);           // NCHUNK*NBKT
    int*   cs          = cd + NCHUNK * NBKT;                  // NCHUNK*NBKT
    int*   btd         = cs + NCHUNK * NBKT;                  // NBKT
    int*   bts         = btd + NBKT;                          // NBKT
    int*   bbd         = bts + NBKT;                          // NBKT+1
    int*   bbs         = bbd + NBKT + 1;                      // NBKT+1
    unsigned int* w1tb = (unsigned int*)(bbs + NBKT + 1);     // 8192 uints (32KB)

    int epc = (E + NCHUNK - 1) / NCHUNK;

    countAB_kernel<<<NCHUNK, 256, 0, stream>>>(src, dst, cd, cs, E, epc);
    scanB1_kernel<<<2 * NBKT, 256, 0, stream>>>(cd, cs, btd, bts);
    scanB2_kernel<<<18, 512, 0, stream>>>(btd, bts, bbd, bbs, W1, w1tb, N, E);
    scatterAB_kernel<<<NCHUNK, 256, 0, stream>>>(src, dst, cd, cs, bbd, bbs,
                                                 pairs, sbytes, E, epc);
    buildDsrc_kernel<<<NB, 256, 0, stream>>>(sbytes, bbs, ninv_out, N);

    conv_kernel<<<(N * 32 + 255) / 256, 256, 0, stream>>>(in_feat, ninv_out, xb, N);

    agg1_kernel<<<NB, 512, 0, stream>>>(xb, pairs, bbd, Bb, ninv_in, N);

    mm1_kernel<<<(N + MM_ROWS - 1) / MM_ROWS, 256, 0, stream>>>(
        Bb, w1tb, b1, ninv_in, ninv_out, W2, t, N);

    final2_kernel<<<NB, 256, 0, stream>>>(t, pairs, bbd, ninv_in, b2, (float*)d_out, N);
}

// Round 11
// 247.245 us; speedup vs baseline: 6.2180x; 6.2180x over previous
//
#include <hip/hip_runtime.h>

#define IN_F 128
#define HID  128
#define NB_SHIFT 8        // 256 nodes per bucket
#define NBKT 512          // padded bucket count (real NB = ceil(N/256) = 391)
#define NCHUNK 256        // edge chunks for count/scatter passes

typedef __bf16 bf16x8 __attribute__((ext_vector_type(8)));
typedef float f32x4 __attribute__((ext_vector_type(4)));
union U8 { uint4 u; bf16x8 v; };

// ---- bf16 helpers (RNE pack, shift-unpack) --------------------------------
__device__ __forceinline__ unsigned int bfround(float x) {
    unsigned int u = __float_as_uint(x);
    return (u + 0x7fffu + ((u >> 16) & 1u)) >> 16;
}
__device__ __forceinline__ unsigned int pack2(float a, float b) {
    return bfround(a) | (bfround(b) << 16);
}
__device__ __forceinline__ float lo_f(unsigned int u) { return __uint_as_float(u << 16); }
__device__ __forceinline__ float hi_f(unsigned int u) { return __uint_as_float(u & 0xffff0000u); }

// ---------------------------------------------------------------------------
// Pass A: per-chunk histograms of BOTH src and dst buckets (LDS atomics)
// ---------------------------------------------------------------------------
__global__ __launch_bounds__(256)
void countAB_kernel(const int* __restrict__ src, const int* __restrict__ dst,
                    int* __restrict__ cd, int* __restrict__ cs, int E, int epc) {
    __shared__ int hd[NBKT], hs[NBKT];
    int tid = threadIdx.x, c = blockIdx.x;
    hd[tid] = 0; hd[tid + 256] = 0; hs[tid] = 0; hs[tid + 256] = 0;
    __syncthreads();
    int lo = c * epc, hi = min(lo + epc, E);
    for (int i = lo + tid; i < hi; i += 256) {
        atomicAdd(&hd[dst[i] >> NB_SHIFT], 1);
        atomicAdd(&hs[src[i] >> NB_SHIFT], 1);
    }
    __syncthreads();
    cd[c * NBKT + tid] = hd[tid]; cd[c * NBKT + tid + 256] = hd[tid + 256];
    cs[c * NBKT + tid] = hs[tid]; cs[c * NBKT + tid + 256] = hs[tid + 256];
}

// ---------------------------------------------------------------------------
// Pass B1: per-bucket exclusive scan over chunks (in place), bucket totals out
// ---------------------------------------------------------------------------
__global__ __launch_bounds__(256)
void scanB1_kernel(int* __restrict__ cd, int* __restrict__ cs,
                   int* __restrict__ btd, int* __restrict__ bts) {
    __shared__ int sd[256];
    int b = blockIdx.x, tid = threadIdx.x;
    int* arr = (b < NBKT) ? cd : cs;
    int* bt  = (b < NBKT) ? btd : bts;
    int col = b & (NBKT - 1);
    int v = arr[tid * NBKT + col];
    sd[tid] = v; __syncthreads();
    for (int off = 1; off < 256; off <<= 1) {
        int t = (tid >= off) ? sd[tid - off] : 0;
        __syncthreads();
        sd[tid] += t;
        __syncthreads();
    }
    arr[tid * NBKT + col] = sd[tid] - v;
    if (tid == 255) bt[col] = sd[255];
}

// ---------------------------------------------------------------------------
// Pass B2: blocks 0,1 = exclusive scans of bucket totals (dst, src);
// blocks 2..17 = pack W1 -> bf16-transposed w1tb [c][k2] (independent work)
// ---------------------------------------------------------------------------
__global__ __launch_bounds__(512)
void scanB2_kernel(const int* __restrict__ btd, const int* __restrict__ bts,
                   int* __restrict__ bbd, int* __restrict__ bbs,
                   int* __restrict__ row_ptr, const float* __restrict__ W1,
                   unsigned int* __restrict__ w1tb, int N, int E) {
    int tid = threadIdx.x;
    if (blockIdx.x >= 2) {
        // pack W1: idx in [0, 8192); c = idx&127 (coalesced reads), k2 = idx>>7
        int idx = (blockIdx.x - 2) * 512 + tid;
        int c = idx & 127, k2 = idx >> 7;
        float a = W1[(2 * k2)     * HID + c];
        float b = W1[(2 * k2 + 1) * HID + c];
        w1tb[c * 64 + k2] = pack2(a, b);
        return;
    }
    __shared__ int sd[512];
    const int* bt = blockIdx.x ? bts : btd;
    int* bb = blockIdx.x ? bbs : bbd;
    int v = bt[tid];
    sd[tid] = v; __syncthreads();
    for (int off = 1; off < 512; off <<= 1) {
        int t = (tid >= off) ? sd[tid - off] : 0;
        __syncthreads();
        sd[tid] += t;
        __syncthreads();
    }
    bb[tid] = sd[tid] - v;
    if (tid == 511) bb[512] = sd[511];  // == E
    if (blockIdx.x == 0 && tid == 0) row_ptr[N] = E;
}

// ---------------------------------------------------------------------------
// Pass C: scatter packed dst-pairs + src low-bytes (LDS cursors)
// ---------------------------------------------------------------------------
__global__ __launch_bounds__(256)
void scatterAB_kernel(const int* __restrict__ src, const int* __restrict__ dst,
                      const int* __restrict__ cd, const int* __restrict__ cs,
                      const int* __restrict__ bbd, const int* __restrict__ bbs,
                      int* __restrict__ pairs, unsigned char* __restrict__ sbytes,
                      int E, int epc) {
    __shared__ int curd[NBKT], curs[NBKT];
    int tid = threadIdx.x, c = blockIdx.x;
    curd[tid]       = cd[c * NBKT + tid]       + bbd[tid];
    curd[tid + 256] = cd[c * NBKT + tid + 256] + bbd[tid + 256];
    curs[tid]       = cs[c * NBKT + tid]       + bbs[tid];
    curs[tid + 256] = cs[c * NBKT + tid + 256] + bbs[tid + 256];
    __syncthreads();
    int lo = c * epc, hi = min(lo + epc, E);
    for (int i = lo + tid; i < hi; i += 256) {
        int s = src[i], d = dst[i];
        int pd = atomicAdd(&curd[d >> NB_SHIFT], 1);
        pairs[pd] = s | ((d & 255) << 17);          // src < 2^17
        int ps = atomicAdd(&curs[s >> NB_SHIFT], 1);
        sbytes[ps] = (unsigned char)(s & 255);
    }
}

// ---------------------------------------------------------------------------
// Pass D fused: blocks [0,NB) = dst counting sort -> row_ptr, ninv_in, eidx;
// blocks [NB,2NB) = src byte histogram -> ninv_out
// ---------------------------------------------------------------------------
__global__ __launch_bounds__(256)
void buildD2_kernel(const int* __restrict__ pairs, const unsigned char* __restrict__ sbytes,
                    const int* __restrict__ bbd, const int* __restrict__ bbs,
                    int* __restrict__ row_ptr, float* __restrict__ ninv_in,
                    float* __restrict__ ninv_out, int* __restrict__ eidx,
                    int N, int NB) {
    __shared__ int cnt[256], sd[256], cursor[256];
    int tid = threadIdx.x;
    if (blockIdx.x >= NB) {
        // ---- src role: byte histogram -> ninv_out
        int b = blockIdx.x - NB;
        int beg = bbs[b], end = bbs[b + 1];
        cnt[tid] = 0;
        __syncthreads();
        for (int i = beg + tid; i < end; i += 256)
            atomicAdd(&cnt[sbytes[i]], 1);
        __syncthreads();
        int node = (b << NB_SHIFT) + tid;
        if (node < N) {
            int v = cnt[tid];
            ninv_out[node] = (v > 0) ? rsqrtf((float)v) : 0.0f;
        }
        return;
    }
    // ---- dst role: counting sort
    int b = blockIdx.x;
    int beg = bbd[b], end = bbd[b + 1];
    cnt[tid] = 0;
    __syncthreads();
    for (int i = beg + tid; i < end; i += 256)
        atomicAdd(&cnt[(pairs[i] >> 17) & 255], 1);
    __syncthreads();
    int v = cnt[tid];
    sd[tid] = v; __syncthreads();
    for (int off = 1; off < 256; off <<= 1) {
        int t = (tid >= off) ? sd[tid - off] : 0;
        __syncthreads();
        sd[tid] += t;
        __syncthreads();
    }
    int excl = sd[tid] - v;
    int node = (b << NB_SHIFT) + tid;
    if (node < N) {
        row_ptr[node] = beg + excl;
        ninv_in[node] = (v > 0) ? rsqrtf((float)v) : 0.0f;
    }
    cursor[tid] = beg + excl;
    __syncthreads();
    for (int i = beg + tid; i < end; i += 256) {
        int p = pairs[i];
        int pos = atomicAdd(&cursor[(p >> 17) & 255], 1);
        eidx[pos] = p & 0x1FFFF;
    }
}

// ---------------------------------------------------------------------------
// conv: xb = bf16(in_feat * ninv_out)
// ---------------------------------------------------------------------------
__global__ __launch_bounds__(256)
void conv_kernel(const float* __restrict__ in_feat, const float* __restrict__ ninv_out,
                 unsigned int* __restrict__ xb, int N) {
    int gid = blockIdx.x * 256 + threadIdx.x;   // [0, N*32)
    if (gid >= N * 32) return;
    int r = gid >> 5, q = gid & 31;
    float no = ninv_out[r];
    float4 v = ((const float4*)in_feat)[(long)r * 32 + q];
    uint2 o;
    o.x = pack2(v.x * no, v.y * no);
    o.y = pack2(v.z * no, v.w * no);
    ((uint2*)xb)[(long)r * 32 + q] = o;
}

// ---------------------------------------------------------------------------
// Layer-1 aggregation (round-6 champion): one WAVE per node, lane owns one
// uint (2 bf16). 8-deep edge unroll -> 8 outstanding 4B gathers per lane.
// ---------------------------------------------------------------------------
__global__ __launch_bounds__(256)
void agg1_kernel(const unsigned int* __restrict__ xb, const int* __restrict__ row_ptr,
                 const int* __restrict__ eidx, unsigned int* __restrict__ Bb, int N) {
    int wave = threadIdx.x >> 6;
    int lane = threadIdx.x & 63;
    int d = blockIdx.x * 4 + wave;
    if (d >= N) return;
    int beg = row_ptr[d], end = row_ptr[d + 1];
    float ax = 0.f, ay = 0.f;
    int j = beg;
    for (; j + 8 <= end; j += 8) {
        int s0 = eidx[j+0], s1 = eidx[j+1], s2 = eidx[j+2], s3 = eidx[j+3];
        int s4 = eidx[j+4], s5 = eidx[j+5], s6 = eidx[j+6], s7 = eidx[j+7];
        unsigned int u0 = xb[(long)s0*64+lane], u1 = xb[(long)s1*64+lane];
        unsigned int u2 = xb[(long)s2*64+lane], u3 = xb[(long)s3*64+lane];
        unsigned int u4 = xb[(long)s4*64+lane], u5 = xb[(long)s5*64+lane];
        unsigned int u6 = xb[(long)s6*64+lane], u7 = xb[(long)s7*64+lane];
        ax += lo_f(u0) + lo_f(u1) + lo_f(u2) + lo_f(u3)
            + lo_f(u4) + lo_f(u5) + lo_f(u6) + lo_f(u7);
        ay += hi_f(u0) + hi_f(u1) + hi_f(u2) + hi_f(u3)
            + hi_f(u4) + hi_f(u5) + hi_f(u6) + hi_f(u7);
    }
    for (; j + 2 <= end; j += 2) {
        unsigned int u0 = xb[(long)eidx[j]*64+lane], u1 = xb[(long)eidx[j+1]*64+lane];
        ax += lo_f(u0) + lo_f(u1);
        ay += hi_f(u0) + hi_f(u1);
    }
    if (j < end) {
        unsigned int u = xb[(long)eidx[j]*64+lane];
        ax += lo_f(u); ay += hi_f(u);
    }
    Bb[(long)d * 64 + lane] = pack2(ax, ay);
}

// ---------------------------------------------------------------------------
// Fused mm1+mm2 via MFMA (bf16 in, f32 accum):
//   t[row] = ninv_out[row] * (relu(B[row]@W1 * ninv_in + b1) @ W2)
// W1 comes prepacked bf16-transposed from global w1tb (coalesced uint4 stage).
// ---------------------------------------------------------------------------
#define MM_ROWS 64
__global__ __launch_bounds__(256)
void mm1_kernel(const unsigned int* __restrict__ Bb, const unsigned int* __restrict__ w1tb,
                const float* __restrict__ b1, const float* __restrict__ ninv_in,
                const float* __restrict__ ninv_out, const float* __restrict__ W2,
                float* __restrict__ t, int N) {
    __shared__ unsigned int w1t[128 * 68];    // [c][k2], padded stride 68
    int tid = threadIdx.x;
    int wave = tid >> 6, lane = tid & 63;
    int row0 = blockIdx.x * MM_ROWS;

    // stage prepacked W1: 2048 uint4, coalesced global -> padded LDS
    {
        const uint4* g = (const uint4*)w1tb;
#pragma unroll
        for (int pass = 0; pass < 8; ++pass) {
            int idx = pass * 256 + tid;       // uint4 index
            int c = idx >> 4, q = idx & 15;
            *(uint4*)&w1t[c * 68 + q * 4] = g[idx];
        }
    }

    // per-lane epilogue constants: cols n = (lane&15) + 16*ct
    int m = lane & 15;
    int kg = lane >> 4;                        // 0..3
    float  b1r[8];
    float2 w2r[8];
    const float2* W2v = (const float2*)W2;
#pragma unroll
    for (int ct = 0; ct < 8; ++ct) {
        int n = m + 16 * ct;
        b1r[ct] = b1[n];
        w2r[ct] = W2v[n];
    }

    // A-fragments: row r, k in [ks*32 + kg*8, +8)  -> uint4 at Bb[r*64+ks*16+kg*4]
    int r = row0 + wave * 16 + m;
    U8 afrag[4];
    if (r < N) {
#pragma unroll
        for (int ks = 0; ks < 4; ++ks)
            afrag[ks].u = *(const uint4*)&Bb[(long)r * 64 + ks * 16 + kg * 4];
    } else {
#pragma unroll
        for (int ks = 0; ks < 4; ++ks)
            afrag[ks].u = make_uint4(0u, 0u, 0u, 0u);
    }
    __syncthreads();

    f32x4 acc[8];
#pragma unroll
    for (int ct = 0; ct < 8; ++ct) acc[ct] = (f32x4){0.f, 0.f, 0.f, 0.f};

#pragma unroll
    for (int ks = 0; ks < 4; ++ks) {
#pragma unroll
        for (int ct = 0; ct < 8; ++ct) {
            U8 bf;
            bf.u = *(const uint4*)&w1t[(m + 16 * ct) * 68 + ks * 16 + kg * 4];
            acc[ct] = __builtin_amdgcn_mfma_f32_16x16x32_bf16(afrag[ks].v, bf.v, acc[ct], 0, 0, 0);
        }
    }

    // epilogue: rows of quarter-group kg: grow = row0 + wave*16 + kg*4 + reg
#pragma unroll
    for (int reg = 0; reg < 4; ++reg) {
        int grow = row0 + wave * 16 + kg * 4 + reg;
        int cg = min(grow, N - 1);
        float ni = ninv_in[cg];
        float p0 = 0.f, p1 = 0.f;
#pragma unroll
        for (int ct = 0; ct < 8; ++ct) {
            float h = fmaxf(acc[ct][reg] * ni + b1r[ct], 0.f);
            p0 += h * w2r[ct].x;
            p1 += h * w2r[ct].y;
        }
#pragma unroll
        for (int off = 8; off >= 1; off >>= 1) {
            p0 += __shfl_xor(p0, off, 16);
            p1 += __shfl_xor(p1, off, 16);
        }
        if (m == 0 && grow < N) {
            float no = ninv_out[grow];
            ((float2*)t)[grow] = make_float2(p0 * no, p1 * no);
        }
    }
}

// ---------------------------------------------------------------------------
// Layer-2 CSR gather fused with epilogue
// ---------------------------------------------------------------------------
__global__ void final2_kernel(const float* __restrict__ t, const int* __restrict__ row_ptr,
                              const int* __restrict__ eidx, const float* __restrict__ ninv_in,
                              const float* __restrict__ b2, float* __restrict__ out, int N) {
    int i = blockIdx.x * blockDim.x + threadIdx.x;
    if (i >= N) return;
    int beg = row_ptr[i], end = row_ptr[i + 1];
    const float2* t2 = (const float2*)t;
    float ax = 0.f, ay = 0.f;
    int j = beg;
    for (; j + 4 <= end; j += 4) {
        float2 v0 = t2[eidx[j]], v1 = t2[eidx[j+1]], v2 = t2[eidx[j+2]], v3 = t2[eidx[j+3]];
        ax += v0.x + v1.x + v2.x + v3.x;
        ay += v0.y + v1.y + v2.y + v3.y;
    }
    for (; j < end; ++j) {
        float2 v = t2[eidx[j]];
        ax += v.x; ay += v.y;
    }
    float ni = ninv_in[i];
    float2 o;
    o.x = ax * ni + b2[0];
    o.y = ay * ni + b2[1];
    ((float2*)out)[i] = o;
}

// ---------------------------------------------------------------------------
extern "C" void kernel_launch(void* const* d_in, const int* in_sizes, int n_in,
                              void* d_out, int out_size, void* d_ws, size_t ws_size,
                              hipStream_t stream) {
    const float* in_feat = (const float*)d_in[0];
    const float* W1      = (const float*)d_in[1];
    const float* b1      = (const float*)d_in[2];
    const float* W2      = (const float*)d_in[3];
    const float* b2      = (const float*)d_in[4];
    const int*   src     = (const int*)d_in[5];
    const int*   dst     = (const int*)d_in[6];
    int N = in_sizes[0] / IN_F;
    int E = in_sizes[5];
    int NB = (N + 255) >> 8;

    unsigned int* Bb  = (unsigned int*)d_ws;
    int*   pairs      = (int*)Bb;                            // E ints (consumed pre-agg1)
    unsigned char* sbytes = (unsigned char*)(Bb + E);        // E bytes (consumed pre-agg1)
    unsigned int* xb  = Bb + (size_t)64 * N;
    float* ninv_out   = (float*)(xb + (size_t)64 * N);       // N
    float* ninv_in    = ninv_out + N;                        // N
    float* t          = ninv_in + N;                         // 2N
    int*   row_ptr    = (int*)(t + (size_t)2 * N);           // N+1
    int*   eidx       = row_ptr + N + 1;                     // E
    int*   cd         = eidx + E;                            // NCHUNK*NBKT
    int*   cs         = cd + NCHUNK * NBKT;                  // NCHUNK*NBKT
    int*   btd        = cs + NCHUNK * NBKT;                  // 512
    int*   bts        = btd + NBKT;                          // 512
    int*   bbd        = bts + NBKT;                          // 513
    int*   bbs        = bbd + NBKT + 1;                      // 513
    unsigned int* w1tb = (unsigned int*)(bbs + NBKT + 1);    // 8192 uints (32KB)

    int epc = (E + NCHUNK - 1) / NCHUNK;

    countAB_kernel<<<NCHUNK, 256, 0, stream>>>(src, dst, cd, cs, E, epc);
    scanB1_kernel<<<2 * NBKT, 256, 0, stream>>>(cd, cs, btd, bts);
    scanB2_kernel<<<18, 512, 0, stream>>>(btd, bts, bbd, bbs, row_ptr, W1, w1tb, N, E);
    scatterAB_kernel<<<NCHUNK, 256, 0, stream>>>(src, dst, cd, cs, bbd, bbs,
                                                 pairs, sbytes, E, epc);
    buildD2_kernel<<<2 * NB, 256, 0, stream>>>(pairs, sbytes, bbd, bbs,
                                               row_ptr, ninv_in, ninv_out, eidx, N, NB);

    conv_kernel<<<(N * 32 + 255) / 256, 256, 0, stream>>>(in_feat, ninv_out, xb, N);

    agg1_kernel<<<(N + 3) / 4, 256, 0, stream>>>(xb, row_ptr, eidx, Bb, N);

    mm1_kernel<<<(N + MM_ROWS - 1) / MM_ROWS, 256, 0, stream>>>(
        Bb, w1tb, b1, ninv_in, ninv_out, W2, t, N);

    final2_kernel<<<(N + 255) / 256, 256, 0, stream>>>(
        t, row_ptr, eidx, ninv_in, b2, (float*)d_out, N);
}